// Round 6
// baseline (370.586 us; speedup 1.0000x reference)
//
#include <hip/hip_runtime.h>
#include <hip/hip_bf16.h>

#define BB 2
#define SS 2048
#define DM 2048
#define NH 16
#define NKV 4
#define DH 128
#define QS 3072   // packed qkv row stride: 2048 q | 512 k | 512 v

typedef __hip_bfloat16 bf16;
typedef short short4v __attribute__((ext_vector_type(4)));
typedef short short8 __attribute__((ext_vector_type(8)));
typedef float floatx4 __attribute__((ext_vector_type(4)));

#if __has_builtin(__builtin_amdgcn_exp2f)
#define EX2(x) __builtin_amdgcn_exp2f(x)
#else
#define EX2(x) exp2f(x)
#endif

__device__ __forceinline__ bf16 f2b(float v) { return __float2bfloat16(v); }
__device__ __forceinline__ short f2bs(float v) {
    bf16 t = __float2bfloat16(v);
    return __builtin_bit_cast(short, t);
}
__device__ __forceinline__ void store_c(bf16* p, float v) { *p = __float2bfloat16(v); }
__device__ __forceinline__ void store_c(float* p, float v) { *p = v; }

// ---------------- x fp32 -> bf16 (vectorized in AND out)
__global__ __launch_bounds__(256) void convert_x(const float4* __restrict__ x,
                                                 bf16* __restrict__ xb, int n4) {
    int i = blockIdx.x * blockDim.x + threadIdx.x;
    if (i >= n4) return;
    float4 v = x[i];
    short4v o;
    o.x = f2bs(v.x); o.y = f2bs(v.y); o.z = f2bs(v.z); o.w = f2bs(v.w);
    *(short4v*)(xb + (size_t)i * 4) = o;
}

// ---------------- weight fp32 [Kd][N] -> bf16 transposed [N][Kd] (wo path)
__global__ __launch_bounds__(256) void convert_wT(const float* __restrict__ w,
                                                  bf16* __restrict__ outT,
                                                  int N, int Kd) {
    const int n0 = blockIdx.x * 64, k0 = blockIdx.y * 64;
    __shared__ float tile[64][65];
    const int tid = threadIdx.x;
    for (int i = tid; i < 4096; i += 256) {
        int r = i >> 6, c = i & 63;  // r: k-local, c: n-local
        tile[r][c] = w[(size_t)(k0 + r) * N + n0 + c];
    }
    __syncthreads();
    for (int i = tid; i < 4096; i += 256) {
        int r = i >> 6, c = i & 63;  // r: n-local, c: k-local
        outT[(size_t)(n0 + r) * Kd + k0 + c] = f2b(tile[c][r]);
    }
}

// ---------------- fused wq|wk|wv fp32 -> bf16 transposed into wqkvT[3072][2048]
__global__ __launch_bounds__(256) void convert_wqkv(const float* __restrict__ wq,
                                                    const float* __restrict__ wk,
                                                    const float* __restrict__ wv,
                                                    bf16* __restrict__ outT) {
    const int bx = blockIdx.x;            // 48 col-tiles of the packed output
    const float* w; int N; int n0;
    if (bx < 32)      { w = wq; N = 2048; n0 = bx * 64; }
    else if (bx < 40) { w = wk; N = 512;  n0 = (bx - 32) * 64; }
    else              { w = wv; N = 512;  n0 = (bx - 40) * 64; }
    const int k0 = blockIdx.y * 64;
    const int gn0 = bx * 64;              // row in packed outT
    __shared__ float tile[64][65];
    const int tid = threadIdx.x;
    for (int i = tid; i < 4096; i += 256) {
        int r = i >> 6, c = i & 63;
        tile[r][c] = w[(size_t)(k0 + r) * N + n0 + c];
    }
    __syncthreads();
    for (int i = tid; i < 4096; i += 256) {
        int r = i >> 6, c = i & 63;
        outT[(size_t)(gn0 + r) * DM + k0 + c] = f2b(tile[c][r]);
    }
}

// ---------------- MFMA GEMM: C[M,N] = A[M,K] @ BT[N,K]^T, bf16 in, fp32 acc
// Round-4 schedule (T4 counted-vmcnt, 2-deep prefetch, triple buffer) +
// round-5 bijective XCD swizzle (T1).
// Round-6: MODE=1 fuses RoPE into the epilogue (qkv GEMM): the RoPE pair
// (2i,2i+1) of a head-dim lives at adjacent columns = adjacent lanes
// (col16, col16^1) -> partner via __shfl_xor(v,1); out = v*cos + sgn*
// partner*sin, sgn = (col odd) ? +1 : -1. Tables indexed [row&2047][(col&127)>>1].
// Applies to cols < 2560 (q|k); v-region stored plain. RoPE on fp32 acc
// (pre-bf16-round) is slightly MORE accurate than the old separate pass.
template <typename TC, int MODE>
__global__ __launch_bounds__(256) void mfma_gemm(const bf16* __restrict__ A,
                                                 const bf16* __restrict__ BT,
                                                 TC* __restrict__ C,
                                                 int M, int N, int K,
                                                 const float* __restrict__ cs,
                                                 const float* __restrict__ sn) {
    __shared__ short As[3][128 * 32];
    __shared__ short Bs[3][128 * 32];
    const int tid = threadIdx.x;
    const int w = tid >> 6, lane = tid & 63;
    const int col16 = lane & 15, quad = lane >> 4;
    // XCD swizzle (bijective: nwg % 8 == 0 for all our grids)
    const int gx = gridDim.x;
    const int nwg = gx * gridDim.y;
    int lin = blockIdx.y * gx + blockIdx.x;
    lin = (lin & 7) * (nwg >> 3) + (lin >> 3);
    const int row0 = (lin / gx) * 128, col0 = (lin % gx) * 128;
    const int wr0 = (w >> 1) * 64, wc0 = (w & 1) * 64;
    const int nt = K / 32;

    auto issue = [&](int t, int b) {
        const int k0 = t * 32;
        #pragma unroll
        for (int it = 0; it < 2; it++) {
            int cc = w * 128 + it * 64 + lane;
            int r = cc >> 2, seg = cc & 3;
            const bf16* g = A + (size_t)(row0 + r) * K + k0 + ((seg ^ (r & 3)) * 8);
            __builtin_amdgcn_global_load_lds(
                (const __attribute__((address_space(1))) unsigned int*)g,
                (__attribute__((address_space(3))) unsigned int*)&As[b][(w * 128 + it * 64) * 8],
                16, 0, 0);
        }
        #pragma unroll
        for (int it = 0; it < 2; it++) {
            int cc = w * 128 + it * 64 + lane;
            int r = cc >> 2, seg = cc & 3;
            const bf16* g = BT + (size_t)(col0 + r) * K + k0 + ((seg ^ (r & 3)) * 8);
            __builtin_amdgcn_global_load_lds(
                (const __attribute__((address_space(1))) unsigned int*)g,
                (__attribute__((address_space(3))) unsigned int*)&Bs[b][(w * 128 + it * 64) * 8],
                16, 0, 0);
        }
    };

    floatx4 acc[4][4];
    #pragma unroll
    for (int mi = 0; mi < 4; mi++)
        #pragma unroll
        for (int ni = 0; ni < 4; ni++) acc[mi][ni] = (floatx4){0.f, 0.f, 0.f, 0.f};

    issue(0, 0);
    if (1 < nt) issue(1, 1);

    for (int t = 0; t < nt; ++t) {
        const int cb = t % 3;
        if (t + 1 < nt) { asm volatile("s_waitcnt vmcnt(4)" ::: "memory"); }
        else            { asm volatile("s_waitcnt vmcnt(0)" ::: "memory"); }
        __builtin_amdgcn_sched_barrier(0);
        __builtin_amdgcn_s_barrier();
        __builtin_amdgcn_sched_barrier(0);
        if (t + 2 < nt) issue(t + 2, (t + 2) % 3);

        short8 af[4], bfr[4];
        #pragma unroll
        for (int mi = 0; mi < 4; mi++) {
            int r = wr0 + mi * 16 + col16;
            af[mi] = *(const short8*)&As[cb][r * 32 + ((quad ^ (r & 3)) * 8)];
        }
        #pragma unroll
        for (int ni = 0; ni < 4; ni++) {
            int r = wc0 + ni * 16 + col16;
            bfr[ni] = *(const short8*)&Bs[cb][r * 32 + ((quad ^ (r & 3)) * 8)];
        }
        __builtin_amdgcn_s_setprio(1);
        #pragma unroll
        for (int mi = 0; mi < 4; mi++)
            #pragma unroll
            for (int ni = 0; ni < 4; ni++)
                acc[mi][ni] = __builtin_amdgcn_mfma_f32_16x16x32_bf16(af[mi], bfr[ni], acc[mi][ni], 0, 0, 0);
        __builtin_amdgcn_s_setprio(0);
    }

    if (MODE == 1 && col0 + wc0 < 2560) {
        // q|k region: apply RoPE on fp32 acc, then store bf16
        #pragma unroll
        for (int ni = 0; ni < 4; ni++) {
            const int ccol = col0 + wc0 + ni * 16 + col16;
            const int ii = (ccol & 127) >> 1;
            const float sgn = (ccol & 1) ? 1.f : -1.f;
            #pragma unroll
            for (int mi = 0; mi < 4; mi++)
                #pragma unroll
                for (int r = 0; r < 4; r++) {
                    const int row = row0 + wr0 + mi * 16 + quad * 4 + r;
                    const int s = row & (SS - 1);
                    float v = acc[mi][ni][r];
                    float other = __shfl_xor(v, 1);
                    float cc = cs[s * 64 + ii];
                    float ssn = sn[s * 64 + ii];
                    store_c(&C[(size_t)row * N + ccol],
                            __builtin_fmaf(v, cc, sgn * other * ssn));
                }
        }
    } else {
        #pragma unroll
        for (int mi = 0; mi < 4; mi++)
            #pragma unroll
            for (int ni = 0; ni < 4; ni++)
                #pragma unroll
                for (int r = 0; r < 4; r++)
                    store_c(&C[(size_t)(row0 + wr0 + mi * 16 + quad * 4 + r) * N +
                               col0 + wc0 + ni * 16 + col16],
                            acc[mi][ni][r]);
    }
}

// ---------------- V transpose: qkv packed v -> vt[b][kvh][d][s]
__global__ __launch_bounds__(256) void transpose_v(const bf16* __restrict__ qkv,
                                                   bf16* __restrict__ vt) {
    const int s0 = blockIdx.x * 64, d0 = blockIdx.y * 64;
    const int b = blockIdx.z >> 2, kvh = blockIdx.z & 3;
    __shared__ bf16 tile[64][65];
    const int tid = threadIdx.x;
    for (int i = tid; i < 4096; i += 256) {
        int r = i >> 6, c = i & 63;
        tile[r][c] = qkv[(size_t)(b * SS + s0 + r) * QS + 2560 + kvh * DH + d0 + c];
    }
    __syncthreads();
    for (int i = tid; i < 4096; i += 256) {
        int r = i >> 6, c = i & 63;
        vt[((size_t)(b * NKV + kvh) * DH + d0 + r) * SS + s0 + c] = tile[c][r];
    }
}

// ---------------- Flash attention (causal, GQA), bf16 MFMA 16x16x32
// Frozen round-5 structure (88.5 us): K/V double-buffered via global_load_lds
// w=16, one barrier/tile, both-sides XOR swizzle; MFMA ones-column row-sum,
// exp2 with folded scale, uniform causal branch, defer-rescale THR=8 nats.
#define PPAD 88

__global__ __launch_bounds__(256) void flash_attn(const bf16* __restrict__ qkv,
                                                  const bf16* __restrict__ vt,
                                                  bf16* __restrict__ ao) {
    const int bx = blockIdx.x, h = blockIdx.y, b = blockIdx.z;
    const int kvh = h >> 2;
    __shared__ short Ks[2][64 * 128];   // [kvrow][d-seg], swizzled segs
    __shared__ short Vs[2][128 * 64];   // [d-row][s-seg], swizzled segs
    __shared__ short Ps[4 * 16 * PPAD];
    const int tid = threadIdx.x;
    const int w = tid >> 6, lane = tid & 63;
    const int col = lane & 15, quad = lane >> 4;
    const int c7 = col & 7;
    const float C = 0.12751746517859245f;  // (1/sqrt(128)) * log2(e)
    const float THR_RAW = 90.5f;           // 8 nats in raw-score units

    const int krl = lane >> 4, kseg = lane & 15;   // K: 4 rows / inst
    const int vrl = lane >> 3, vseg = lane & 7;    // V: 8 rows / inst

    const bf16* kgb = qkv + (size_t)b * SS * QS + 2048 + kvh * DH;
    const bf16* vgb = vt + (size_t)(b * NKV + kvh) * DH * SS;

    const short8 vone = {0x3F80, 0x3F80, 0x3F80, 0x3F80, 0x3F80, 0x3F80, 0x3F80, 0x3F80};

    for (int phase = 0; phase < 2; phase++) {
        const int qt = phase == 0 ? bx : (SS / 64 - 1 - bx);
        const int q0 = qt * 64;

        short8 aq[4];
        const bf16* qbase = qkv + (size_t)(b * SS + q0 + w * 16 + col) * QS + h * DH;
        #pragma unroll
        for (int kc = 0; kc < 4; kc++)
            aq[kc] = *(const short8*)(qbase + kc * 32 + quad * 8);

        floatx4 o[8];
        #pragma unroll
        for (int dt = 0; dt < 8; dt++) o[dt] = (floatx4){0.f, 0.f, 0.f, 0.f};
        floatx4 oL = (floatx4){0.f, 0.f, 0.f, 0.f};
        float mrow[4] = {-3e38f, -3e38f, -3e38f, -3e38f};

        for (int kt = 0; kt <= qt; kt++) {
            const int cur = kt & 1;
            __syncthreads();
            if (kt == 0) {
                #pragma unroll
                for (int it = 0; it < 4; it++) {
                    int row = w * 16 + it * 4 + krl;
                    const bf16* g = kgb + (size_t)row * QS + ((kseg ^ (row & 7)) * 8);
                    __builtin_amdgcn_global_load_lds(
                        (const __attribute__((address_space(1))) unsigned int*)g,
                        (__attribute__((address_space(3))) unsigned int*)&Ks[0][(w * 16 + it * 4) * 128],
                        16, 0, 0);
                }
                #pragma unroll
                for (int it = 0; it < 4; it++) {
                    int drow = w * 32 + it * 8 + vrl;
                    const bf16* g = vgb + (size_t)drow * SS + ((vseg ^ (drow & 7)) * 8);
                    __builtin_amdgcn_global_load_lds(
                        (const __attribute__((address_space(1))) unsigned int*)g,
                        (__attribute__((address_space(3))) unsigned int*)&Vs[0][(w * 32 + it * 8) * 64],
                        16, 0, 0);
                }
                __syncthreads();
            }
            if (kt < qt) {
                const int nk0 = (kt + 1) * 64;
                #pragma unroll
                for (int it = 0; it < 4; it++) {
                    int row = w * 16 + it * 4 + krl;
                    const bf16* g = kgb + (size_t)(nk0 + row) * QS + ((kseg ^ (row & 7)) * 8);
                    __builtin_amdgcn_global_load_lds(
                        (const __attribute__((address_space(1))) unsigned int*)g,
                        (__attribute__((address_space(3))) unsigned int*)&Ks[cur ^ 1][(w * 16 + it * 4) * 128],
                        16, 0, 0);
                }
                #pragma unroll
                for (int it = 0; it < 4; it++) {
                    int drow = w * 32 + it * 8 + vrl;
                    const bf16* g = vgb + (size_t)drow * SS + nk0 + ((vseg ^ (drow & 7)) * 8);
                    __builtin_amdgcn_global_load_lds(
                        (const __attribute__((address_space(1))) unsigned int*)g,
                        (__attribute__((address_space(3))) unsigned int*)&Vs[cur ^ 1][(w * 32 + it * 8) * 64],
                        16, 0, 0);
                }
            }

            const int k0 = kt * 64;
            floatx4 s[4];
            __builtin_amdgcn_s_setprio(1);
            #pragma unroll
            for (int n = 0; n < 4; n++) {
                s[n] = (floatx4){0.f, 0.f, 0.f, 0.f};
                #pragma unroll
                for (int kc = 0; kc < 4; kc++) {
                    short8 bk = *(const short8*)&Ks[cur][(n * 16 + col) * 128 + (((kc * 4 + quad) ^ c7) * 8)];
                    s[n] = __builtin_amdgcn_mfma_f32_16x16x32_bf16(aq[kc], bk, s[n], 0, 0, 0);
                }
            }
            __builtin_amdgcn_s_setprio(0);

            if (kt == qt) {
                #pragma unroll
                for (int n = 0; n < 4; n++)
                    #pragma unroll
                    for (int r = 0; r < 4; r++)
                        if ((k0 + n * 16 + col) > (q0 + w * 16 + quad * 4 + r)) s[n][r] = -3e38f;
            }

            float rmx[4];
            #pragma unroll
            for (int r = 0; r < 4; r++) {
                float rm = fmaxf(fmaxf(s[0][r], s[1][r]), fmaxf(s[2][r], s[3][r]));
                rm = fmaxf(rm, __shfl_xor(rm, 1));
                rm = fmaxf(rm, __shfl_xor(rm, 2));
                rm = fmaxf(rm, __shfl_xor(rm, 4));
                rm = fmaxf(rm, __shfl_xor(rm, 8));
                rmx[r] = fmaxf(rm, mrow[r]);
            }
            bool need = (rmx[0] - mrow[0] > THR_RAW) | (rmx[1] - mrow[1] > THR_RAW) |
                        (rmx[2] - mrow[2] > THR_RAW) | (rmx[3] - mrow[3] > THR_RAW);
            if (__any((int)need)) {
                float al[4];
                #pragma unroll
                for (int r = 0; r < 4; r++) {
                    al[r] = EX2((mrow[r] - rmx[r]) * C);
                    mrow[r] = rmx[r];
                }
                #pragma unroll
                for (int dt = 0; dt < 8; dt++)
                    #pragma unroll
                    for (int r = 0; r < 4; r++) o[dt][r] *= al[r];
                #pragma unroll
                for (int r = 0; r < 4; r++) oL[r] *= al[r];
            }
            float mC[4];
            #pragma unroll
            for (int r = 0; r < 4; r++) mC[r] = mrow[r] * C;

            short* pw = &Ps[w * 16 * PPAD];
            #pragma unroll
            for (int n = 0; n < 4; n++)
                #pragma unroll
                for (int r = 0; r < 4; r++)
                    pw[(quad * 4 + r) * PPAD + n * 16 + col] =
                        f2bs(EX2(__builtin_fmaf(s[n][r], C, -mC[r])));

            short8 ap0 = *(const short8*)&pw[col * PPAD + quad * 8];
            short8 ap1 = *(const short8*)&pw[col * PPAD + 32 + quad * 8];
            __builtin_amdgcn_s_setprio(1);
            #pragma unroll
            for (int dt = 0; dt < 8; dt++) {
                short8 bv0 = *(const short8*)&Vs[cur][(dt * 16 + col) * 64 + ((quad ^ c7) * 8)];
                o[dt] = __builtin_amdgcn_mfma_f32_16x16x32_bf16(ap0, bv0, o[dt], 0, 0, 0);
                short8 bv1 = *(const short8*)&Vs[cur][(dt * 16 + col) * 64 + (((quad + 4) ^ c7) * 8)];
                o[dt] = __builtin_amdgcn_mfma_f32_16x16x32_bf16(ap1, bv1, o[dt], 0, 0, 0);
            }
            oL = __builtin_amdgcn_mfma_f32_16x16x32_bf16(ap0, vone, oL, 0, 0, 0);
            oL = __builtin_amdgcn_mfma_f32_16x16x32_bf16(ap1, vone, oL, 0, 0, 0);
            __builtin_amdgcn_s_setprio(0);
        }
        #pragma unroll
        for (int r = 0; r < 4; r++) {
            float inv = 1.f / oL[r];
            int srow = q0 + w * 16 + quad * 4 + r;
            bf16* op = ao + ((size_t)(b * SS + srow) * NH + h) * DH;
            #pragma unroll
            for (int dt = 0; dt < 8; dt++)
                op[dt * 16 + col] = f2b(o[dt][r] * inv);
        }
    }
}

extern "C" void kernel_launch(void* const* d_in, const int* in_sizes, int n_in,
                              void* d_out, int out_size, void* d_ws, size_t ws_size,
                              hipStream_t stream) {
    const float* x  = (const float*)d_in[0];
    const float* fc = (const float*)d_in[1];
    const float* fs = (const float*)d_in[2];
    // d_in[3] = mask: exactly causal -> implemented directly
    const float* wq = (const float*)d_in[4];
    const float* wk = (const float*)d_in[5];
    const float* wv = (const float*)d_in[6];
    const float* wo = (const float*)d_in[7];
    float* out = (float*)d_out;

    const int M = BB * SS;  // 4096
    bf16* qkv    = (bf16*)d_ws;
    bf16* xb     = qkv + (size_t)M * QS;
    bf16* wqkvT  = xb + (size_t)M * DM;
    bf16* ao     = xb;                        // alias: xb dead after qkv GEMM
    bf16* vt     = wqkvT;                     // alias: wqkvT dead after qkv GEMM
    bf16* woT    = qkv;                       // alias: qkv dead after flash

    dim3 blk(256);
    convert_x<<<(M * DM / 4 + 255) / 256, blk, 0, stream>>>((const float4*)x, xb, M * DM / 4);
    convert_wqkv<<<dim3(QS / 64, DM / 64), blk, 0, stream>>>(wq, wk, wv, wqkvT);

    // qkv projection with fused RoPE epilogue
    mfma_gemm<bf16, 1><<<dim3(QS / 128, M / 128), blk, 0, stream>>>(xb, wqkvT, qkv, M, QS, DM, fc, fs);

    transpose_v<<<dim3(SS / 64, DH / 64, BB * NKV), blk, 0, stream>>>(qkv, vt);

    flash_attn<<<dim3(SS / 128, NH, BB), blk, 0, stream>>>(qkv, vt, ao);

    convert_wT<<<dim3(DM / 64, DM / 64), blk, 0, stream>>>(wo, woT, DM, DM);
    mfma_gemm<float, 0><<<dim3(DM / 128, M / 128), blk, 0, stream>>>(ao, woT, out, M, DM, DM, nullptr, nullptr);
}

// Round 8
// 338.589 us; speedup vs baseline: 1.0945x; 1.0945x over previous
//
#include <hip/hip_runtime.h>
#include <hip/hip_bf16.h>

#define BB 2
#define SS 2048
#define DM 2048
#define NH 16
#define NKV 4
#define DH 128
#define QS 3072   // packed qkv row stride: 2048 q | 512 k | 512 v

typedef __hip_bfloat16 bf16;
typedef short short4v __attribute__((ext_vector_type(4)));
typedef short short8 __attribute__((ext_vector_type(8)));
typedef float floatx4 __attribute__((ext_vector_type(4)));

#if __has_builtin(__builtin_amdgcn_exp2f)
#define EX2(x) __builtin_amdgcn_exp2f(x)
#else
#define EX2(x) exp2f(x)
#endif

__device__ __forceinline__ bf16 f2b(float v) { return __float2bfloat16(v); }
__device__ __forceinline__ short f2bs(float v) {
    bf16 t = __float2bfloat16(v);
    return __builtin_bit_cast(short, t);
}
__device__ __forceinline__ void store_c(bf16* p, float v) { *p = __float2bfloat16(v); }
__device__ __forceinline__ void store_c(float* p, float v) { *p = v; }

// ---------------- x fp32 -> bf16 (vectorized in AND out)
__global__ __launch_bounds__(256) void convert_x(const float4* __restrict__ x,
                                                 bf16* __restrict__ xb, int n4) {
    int i = blockIdx.x * blockDim.x + threadIdx.x;
    if (i >= n4) return;
    float4 v = x[i];
    short4v o;
    o.x = f2bs(v.x); o.y = f2bs(v.y); o.z = f2bs(v.z); o.w = f2bs(v.w);
    *(short4v*)(xb + (size_t)i * 4) = o;
}

// ---------------- weight fp32 [Kd][N] -> bf16 transposed [N][Kd] (wo path)
__global__ __launch_bounds__(256) void convert_wT(const float* __restrict__ w,
                                                  bf16* __restrict__ outT,
                                                  int N, int Kd) {
    const int n0 = blockIdx.x * 64, k0 = blockIdx.y * 64;
    __shared__ float tile[64][65];
    const int tid = threadIdx.x;
    for (int i = tid; i < 4096; i += 256) {
        int r = i >> 6, c = i & 63;  // r: k-local, c: n-local
        tile[r][c] = w[(size_t)(k0 + r) * N + n0 + c];
    }
    __syncthreads();
    for (int i = tid; i < 4096; i += 256) {
        int r = i >> 6, c = i & 63;  // r: n-local, c: k-local
        outT[(size_t)(n0 + r) * Kd + k0 + c] = f2b(tile[c][r]);
    }
}

// ---------------- fused wq|wk|wv fp32 -> bf16 transposed into wqkvT[3072][2048]
__global__ __launch_bounds__(256) void convert_wqkv(const float* __restrict__ wq,
                                                    const float* __restrict__ wk,
                                                    const float* __restrict__ wv,
                                                    bf16* __restrict__ outT) {
    const int bx = blockIdx.x;            // 48 col-tiles of the packed output
    const float* w; int N; int n0;
    if (bx < 32)      { w = wq; N = 2048; n0 = bx * 64; }
    else if (bx < 40) { w = wk; N = 512;  n0 = (bx - 32) * 64; }
    else              { w = wv; N = 512;  n0 = (bx - 40) * 64; }
    const int k0 = blockIdx.y * 64;
    const int gn0 = bx * 64;              // row in packed outT
    __shared__ float tile[64][65];
    const int tid = threadIdx.x;
    for (int i = tid; i < 4096; i += 256) {
        int r = i >> 6, c = i & 63;
        tile[r][c] = w[(size_t)(k0 + r) * N + n0 + c];
    }
    __syncthreads();
    for (int i = tid; i < 4096; i += 256) {
        int r = i >> 6, c = i & 63;
        outT[(size_t)(gn0 + r) * DM + k0 + c] = f2b(tile[c][r]);
    }
}

// ---------------- MFMA GEMM: C[M,N] = A[M,K] @ BT[N,K]^T, bf16 in, fp32 acc
// Round-7: reverted the RoPE epilogue (round-6 regression), and removed the
// sched_barrier(0) pair + setprio from the K-loop: m141 shows sched_barrier(0)
// order-pinning defeats the compiler's own MFMA/ds_read interleave; m190
// shows setprio is ~0/negative on barrier-lockstep GEMMs. Safety: the asm
// "memory" clobber on the s_waitcnt prevents ds_reads hoisting above the
// wait+barrier; MFMAs are data-dependent on the ds_reads.
// Kept: counted vmcnt(4), 2-deep prefetch, triple buffer, seg-XOR swizzle,
// bijective XCD swizzle (nwg%8==0 for both grids).
template <typename TC>
__global__ __launch_bounds__(256) void mfma_gemm(const bf16* __restrict__ A,
                                                 const bf16* __restrict__ BT,
                                                 TC* __restrict__ C,
                                                 int M, int N, int K) {
    __shared__ short As[3][128 * 32];
    __shared__ short Bs[3][128 * 32];
    const int tid = threadIdx.x;
    const int w = tid >> 6, lane = tid & 63;
    const int col16 = lane & 15, quad = lane >> 4;
    const int gx = gridDim.x;
    const int nwg = gx * gridDim.y;
    int lin = blockIdx.y * gx + blockIdx.x;
    lin = (lin & 7) * (nwg >> 3) + (lin >> 3);
    const int row0 = (lin / gx) * 128, col0 = (lin % gx) * 128;
    const int wr0 = (w >> 1) * 64, wc0 = (w & 1) * 64;
    const int nt = K / 32;

    auto issue = [&](int t, int b) {
        const int k0 = t * 32;
        #pragma unroll
        for (int it = 0; it < 2; it++) {
            int cc = w * 128 + it * 64 + lane;
            int r = cc >> 2, seg = cc & 3;
            const bf16* g = A + (size_t)(row0 + r) * K + k0 + ((seg ^ (r & 3)) * 8);
            __builtin_amdgcn_global_load_lds(
                (const __attribute__((address_space(1))) unsigned int*)g,
                (__attribute__((address_space(3))) unsigned int*)&As[b][(w * 128 + it * 64) * 8],
                16, 0, 0);
        }
        #pragma unroll
        for (int it = 0; it < 2; it++) {
            int cc = w * 128 + it * 64 + lane;
            int r = cc >> 2, seg = cc & 3;
            const bf16* g = BT + (size_t)(col0 + r) * K + k0 + ((seg ^ (r & 3)) * 8);
            __builtin_amdgcn_global_load_lds(
                (const __attribute__((address_space(1))) unsigned int*)g,
                (__attribute__((address_space(3))) unsigned int*)&Bs[b][(w * 128 + it * 64) * 8],
                16, 0, 0);
        }
    };

    floatx4 acc[4][4];
    #pragma unroll
    for (int mi = 0; mi < 4; mi++)
        #pragma unroll
        for (int ni = 0; ni < 4; ni++) acc[mi][ni] = (floatx4){0.f, 0.f, 0.f, 0.f};

    issue(0, 0);
    if (1 < nt) issue(1, 1);

    for (int t = 0; t < nt; ++t) {
        const int cb = t % 3;
        if (t + 1 < nt) { asm volatile("s_waitcnt vmcnt(4)" ::: "memory"); }
        else            { asm volatile("s_waitcnt vmcnt(0)" ::: "memory"); }
        __builtin_amdgcn_s_barrier();
        if (t + 2 < nt) issue(t + 2, (t + 2) % 3);

        short8 af[4], bfr[4];
        #pragma unroll
        for (int mi = 0; mi < 4; mi++) {
            int r = wr0 + mi * 16 + col16;
            af[mi] = *(const short8*)&As[cb][r * 32 + ((quad ^ (r & 3)) * 8)];
        }
        #pragma unroll
        for (int ni = 0; ni < 4; ni++) {
            int r = wc0 + ni * 16 + col16;
            bfr[ni] = *(const short8*)&Bs[cb][r * 32 + ((quad ^ (r & 3)) * 8)];
        }
        #pragma unroll
        for (int mi = 0; mi < 4; mi++)
            #pragma unroll
            for (int ni = 0; ni < 4; ni++)
                acc[mi][ni] = __builtin_amdgcn_mfma_f32_16x16x32_bf16(af[mi], bfr[ni], acc[mi][ni], 0, 0, 0);
    }
    #pragma unroll
    for (int mi = 0; mi < 4; mi++)
        #pragma unroll
        for (int ni = 0; ni < 4; ni++)
            #pragma unroll
            for (int r = 0; r < 4; r++)
                store_c(&C[(size_t)(row0 + wr0 + mi * 16 + quad * 4 + r) * N +
                           col0 + wc0 + ni * 16 + col16],
                        acc[mi][ni][r]);
}

// ---------------- RoPE (interleaved pairs) on packed qkv — q and k in one launch
__global__ void rope_all(bf16* __restrict__ qkv, const float* __restrict__ cs,
                         const float* __restrict__ sn, int totq, int total) {
    int idx = blockIdx.x * blockDim.x + threadIdx.x;
    if (idx >= total) return;
    bf16* base; int n_heads; int rel;
    if (idx < totq) { base = qkv;        n_heads = NH;  rel = idx; }
    else            { base = qkv + 2048; n_heads = NKV; rel = idx - totq; }
    int i = rel & 63;
    int h = (rel >> 6) % n_heads;
    size_t bs = (size_t)rel / (64 * n_heads);
    int s = (int)(bs % SS);
    float c = cs[s * 64 + i];
    float si = sn[s * 64 + i];
    bf16* p = base + bs * QS + h * DH + 2 * i;
    float xr = __bfloat162float(p[0]), xi = __bfloat162float(p[1]);
    p[0] = f2b(xr * c - xi * si);
    p[1] = f2b(xr * si + xi * c);
}

// ---------------- V transpose: qkv packed v -> vt[b][kvh][d][s]
__global__ __launch_bounds__(256) void transpose_v(const bf16* __restrict__ qkv,
                                                   bf16* __restrict__ vt) {
    const int s0 = blockIdx.x * 64, d0 = blockIdx.y * 64;
    const int b = blockIdx.z >> 2, kvh = blockIdx.z & 3;
    __shared__ bf16 tile[64][65];
    const int tid = threadIdx.x;
    for (int i = tid; i < 4096; i += 256) {
        int r = i >> 6, c = i & 63;
        tile[r][c] = qkv[(size_t)(b * SS + s0 + r) * QS + 2560 + kvh * DH + d0 + c];
    }
    __syncthreads();
    for (int i = tid; i < 4096; i += 256) {
        int r = i >> 6, c = i & 63;
        vt[((size_t)(b * NKV + kvh) * DH + d0 + r) * SS + s0 + c] = tile[c][r];
    }
}

// ---------------- Flash attention (causal, GQA), bf16 MFMA 16x16x32
// Frozen round-5 structure (88.5 us): K/V double-buffered via global_load_lds
// w=16, one barrier/tile, both-sides XOR swizzle; MFMA ones-column row-sum,
// exp2 with folded scale, uniform causal branch, defer-rescale THR=8 nats.
#define PPAD 88

__global__ __launch_bounds__(256) void flash_attn(const bf16* __restrict__ qkv,
                                                  const bf16* __restrict__ vt,
                                                  bf16* __restrict__ ao) {
    const int bx = blockIdx.x, h = blockIdx.y, b = blockIdx.z;
    const int kvh = h >> 2;
    __shared__ short Ks[2][64 * 128];   // [kvrow][d-seg], swizzled segs
    __shared__ short Vs[2][128 * 64];   // [d-row][s-seg], swizzled segs
    __shared__ short Ps[4 * 16 * PPAD];
    const int tid = threadIdx.x;
    const int w = tid >> 6, lane = tid & 63;
    const int col = lane & 15, quad = lane >> 4;
    const int c7 = col & 7;
    const float C = 0.12751746517859245f;  // (1/sqrt(128)) * log2(e)
    const float THR_RAW = 90.5f;           // 8 nats in raw-score units

    const int krl = lane >> 4, kseg = lane & 15;   // K: 4 rows / inst
    const int vrl = lane >> 3, vseg = lane & 7;    // V: 8 rows / inst

    const bf16* kgb = qkv + (size_t)b * SS * QS + 2048 + kvh * DH;
    const bf16* vgb = vt + (size_t)(b * NKV + kvh) * DH * SS;

    const short8 vone = {0x3F80, 0x3F80, 0x3F80, 0x3F80, 0x3F80, 0x3F80, 0x3F80, 0x3F80};

    for (int phase = 0; phase < 2; phase++) {
        const int qt = phase == 0 ? bx : (SS / 64 - 1 - bx);
        const int q0 = qt * 64;

        short8 aq[4];
        const bf16* qbase = qkv + (size_t)(b * SS + q0 + w * 16 + col) * QS + h * DH;
        #pragma unroll
        for (int kc = 0; kc < 4; kc++)
            aq[kc] = *(const short8*)(qbase + kc * 32 + quad * 8);

        floatx4 o[8];
        #pragma unroll
        for (int dt = 0; dt < 8; dt++) o[dt] = (floatx4){0.f, 0.f, 0.f, 0.f};
        floatx4 oL = (floatx4){0.f, 0.f, 0.f, 0.f};
        float mrow[4] = {-3e38f, -3e38f, -3e38f, -3e38f};

        for (int kt = 0; kt <= qt; kt++) {
            const int cur = kt & 1;
            __syncthreads();
            if (kt == 0) {
                #pragma unroll
                for (int it = 0; it < 4; it++) {
                    int row = w * 16 + it * 4 + krl;
                    const bf16* g = kgb + (size_t)row * QS + ((kseg ^ (row & 7)) * 8);
                    __builtin_amdgcn_global_load_lds(
                        (const __attribute__((address_space(1))) unsigned int*)g,
                        (__attribute__((address_space(3))) unsigned int*)&Ks[0][(w * 16 + it * 4) * 128],
                        16, 0, 0);
                }
                #pragma unroll
                for (int it = 0; it < 4; it++) {
                    int drow = w * 32 + it * 8 + vrl;
                    const bf16* g = vgb + (size_t)drow * SS + ((vseg ^ (drow & 7)) * 8);
                    __builtin_amdgcn_global_load_lds(
                        (const __attribute__((address_space(1))) unsigned int*)g,
                        (__attribute__((address_space(3))) unsigned int*)&Vs[0][(w * 32 + it * 8) * 64],
                        16, 0, 0);
                }
                __syncthreads();
            }
            if (kt < qt) {
                const int nk0 = (kt + 1) * 64;
                #pragma unroll
                for (int it = 0; it < 4; it++) {
                    int row = w * 16 + it * 4 + krl;
                    const bf16* g = kgb + (size_t)(nk0 + row) * QS + ((kseg ^ (row & 7)) * 8);
                    __builtin_amdgcn_global_load_lds(
                        (const __attribute__((address_space(1))) unsigned int*)g,
                        (__attribute__((address_space(3))) unsigned int*)&Ks[cur ^ 1][(w * 16 + it * 4) * 128],
                        16, 0, 0);
                }
                #pragma unroll
                for (int it = 0; it < 4; it++) {
                    int drow = w * 32 + it * 8 + vrl;
                    const bf16* g = vgb + (size_t)drow * SS + nk0 + ((vseg ^ (drow & 7)) * 8);
                    __builtin_amdgcn_global_load_lds(
                        (const __attribute__((address_space(1))) unsigned int*)g,
                        (__attribute__((address_space(3))) unsigned int*)&Vs[cur ^ 1][(w * 32 + it * 8) * 64],
                        16, 0, 0);
                }
            }

            const int k0 = kt * 64;
            floatx4 s[4];
            __builtin_amdgcn_s_setprio(1);
            #pragma unroll
            for (int n = 0; n < 4; n++) {
                s[n] = (floatx4){0.f, 0.f, 0.f, 0.f};
                #pragma unroll
                for (int kc = 0; kc < 4; kc++) {
                    short8 bk = *(const short8*)&Ks[cur][(n * 16 + col) * 128 + (((kc * 4 + quad) ^ c7) * 8)];
                    s[n] = __builtin_amdgcn_mfma_f32_16x16x32_bf16(aq[kc], bk, s[n], 0, 0, 0);
                }
            }
            __builtin_amdgcn_s_setprio(0);

            if (kt == qt) {
                #pragma unroll
                for (int n = 0; n < 4; n++)
                    #pragma unroll
                    for (int r = 0; r < 4; r++)
                        if ((k0 + n * 16 + col) > (q0 + w * 16 + quad * 4 + r)) s[n][r] = -3e38f;
            }

            float rmx[4];
            #pragma unroll
            for (int r = 0; r < 4; r++) {
                float rm = fmaxf(fmaxf(s[0][r], s[1][r]), fmaxf(s[2][r], s[3][r]));
                rm = fmaxf(rm, __shfl_xor(rm, 1));
                rm = fmaxf(rm, __shfl_xor(rm, 2));
                rm = fmaxf(rm, __shfl_xor(rm, 4));
                rm = fmaxf(rm, __shfl_xor(rm, 8));
                rmx[r] = fmaxf(rm, mrow[r]);
            }
            bool need = (rmx[0] - mrow[0] > THR_RAW) | (rmx[1] - mrow[1] > THR_RAW) |
                        (rmx[2] - mrow[2] > THR_RAW) | (rmx[3] - mrow[3] > THR_RAW);
            if (__any((int)need)) {
                float al[4];
                #pragma unroll
                for (int r = 0; r < 4; r++) {
                    al[r] = EX2((mrow[r] - rmx[r]) * C);
                    mrow[r] = rmx[r];
                }
                #pragma unroll
                for (int dt = 0; dt < 8; dt++)
                    #pragma unroll
                    for (int r = 0; r < 4; r++) o[dt][r] *= al[r];
                #pragma unroll
                for (int r = 0; r < 4; r++) oL[r] *= al[r];
            }
            float mC[4];
            #pragma unroll
            for (int r = 0; r < 4; r++) mC[r] = mrow[r] * C;

            short* pw = &Ps[w * 16 * PPAD];
            #pragma unroll
            for (int n = 0; n < 4; n++)
                #pragma unroll
                for (int r = 0; r < 4; r++)
                    pw[(quad * 4 + r) * PPAD + n * 16 + col] =
                        f2bs(EX2(__builtin_fmaf(s[n][r], C, -mC[r])));

            short8 ap0 = *(const short8*)&pw[col * PPAD + quad * 8];
            short8 ap1 = *(const short8*)&pw[col * PPAD + 32 + quad * 8];
            __builtin_amdgcn_s_setprio(1);
            #pragma unroll
            for (int dt = 0; dt < 8; dt++) {
                short8 bv0 = *(const short8*)&Vs[cur][(dt * 16 + col) * 64 + ((quad ^ c7) * 8)];
                o[dt] = __builtin_amdgcn_mfma_f32_16x16x32_bf16(ap0, bv0, o[dt], 0, 0, 0);
                short8 bv1 = *(const short8*)&Vs[cur][(dt * 16 + col) * 64 + (((quad + 4) ^ c7) * 8)];
                o[dt] = __builtin_amdgcn_mfma_f32_16x16x32_bf16(ap1, bv1, o[dt], 0, 0, 0);
            }
            oL = __builtin_amdgcn_mfma_f32_16x16x32_bf16(ap0, vone, oL, 0, 0, 0);
            oL = __builtin_amdgcn_mfma_f32_16x16x32_bf16(ap1, vone, oL, 0, 0, 0);
            __builtin_amdgcn_s_setprio(0);
        }
        #pragma unroll
        for (int r = 0; r < 4; r++) {
            float inv = 1.f / oL[r];
            int srow = q0 + w * 16 + quad * 4 + r;
            bf16* op = ao + ((size_t)(b * SS + srow) * NH + h) * DH;
            #pragma unroll
            for (int dt = 0; dt < 8; dt++)
                op[dt * 16 + col] = f2b(o[dt][r] * inv);
        }
    }
}

extern "C" void kernel_launch(void* const* d_in, const int* in_sizes, int n_in,
                              void* d_out, int out_size, void* d_ws, size_t ws_size,
                              hipStream_t stream) {
    const float* x  = (const float*)d_in[0];
    const float* fc = (const float*)d_in[1];
    const float* fs = (const float*)d_in[2];
    // d_in[3] = mask: exactly causal -> implemented directly
    const float* wq = (const float*)d_in[4];
    const float* wk = (const float*)d_in[5];
    const float* wv = (const float*)d_in[6];
    const float* wo = (const float*)d_in[7];
    float* out = (float*)d_out;

    const int M = BB * SS;  // 4096
    bf16* qkv    = (bf16*)d_ws;
    bf16* xb     = qkv + (size_t)M * QS;
    bf16* wqkvT  = xb + (size_t)M * DM;
    bf16* ao     = xb;                        // alias: xb dead after qkv GEMM
    bf16* vt     = wqkvT;                     // alias: wqkvT dead after qkv GEMM
    bf16* woT    = qkv;                       // alias: qkv dead after flash

    dim3 blk(256);
    convert_x<<<(M * DM / 4 + 255) / 256, blk, 0, stream>>>((const float4*)x, xb, M * DM / 4);
    convert_wqkv<<<dim3(QS / 64, DM / 64), blk, 0, stream>>>(wq, wk, wv, wqkvT);

    mfma_gemm<bf16><<<dim3(QS / 128, M / 128), blk, 0, stream>>>(xb, wqkvT, qkv, M, QS, DM);

    const int totq = BB * SS * NH * 64;
    const int totk = BB * SS * NKV * 64;
    rope_all<<<(totq + totk + 255) / 256, blk, 0, stream>>>(qkv, fc, fs, totq, totq + totk);

    transpose_v<<<dim3(SS / 64, DH / 64, BB * NKV), blk, 0, stream>>>(qkv, vt);

    flash_attn<<<dim3(SS / 128, NH, BB), blk, 0, stream>>>(qkv, vt, ao);

    convert_wT<<<dim3(DM / 64, DM / 64), blk, 0, stream>>>(wo, woT, DM, DM);
    mfma_gemm<float><<<dim3(DM / 128, M / 128), blk, 0, stream>>>(ao, woT, out, M, DM, DM);
}